// Round 7
// baseline (215.369 us; speedup 1.0000x reference)
//
#include <hip/hip_runtime.h>
#include <hip/hip_bf16.h>

typedef __attribute__((ext_vector_type(4))) float f32x4_t;
typedef __attribute__((ext_vector_type(8))) short bf16x8_t;

__device__ __forceinline__ short f2bfs(float x) {
    union { __hip_bfloat16 h; short s; } u;
    u.h = __float2bfloat16(x);   // RNE
    return u.s;
}

// ---------------------------------------------------------------------------
// Kernel 1: build fused 512x512 operator M in fragment-major bf16 layout.
//   c = m*32+o (output col of GEMM), k = n2*32+f (contraction index)
//   M[c][k] = diag[m] * sum_{n,m2} basis[m,n] * Wbig[o,n,f,m2] * basis[n2,m2]
// B-fragment layout for mfma_f32_16x16x32_bf16:
//   flat ushort idx = ((ks*32 + c16)*64 + lane)*8 + j
//   value = M[c16*16 + (lane&15)][ks*32 + (lane>>4)*8 + j]
// ---------------------------------------------------------------------------
__global__ void build_M_kernel(const float* __restrict__ basis,
                               const float* __restrict__ adj,
                               const float* __restrict__ e,
                               const float* __restrict__ We,
                               const float* __restrict__ W2,
                               const float* __restrict__ W3,
                               unsigned short* __restrict__ Mfrag) {
    const int t = blockIdx.x * blockDim.x + threadIdx.x;  // 0..262143
    const int c = t >> 9;           // 0..511
    const int k = t & 511;
    const int m  = c >> 5, o = c & 31;
    const int n2 = k >> 5, f = k & 31;

    float lv[16];
    float mx = -3.4e38f;
#pragma unroll
    for (int j = 0; j < 16; ++j) {
        float a = adj[m * 16 + j];
        float v = (a > 0.0f) ? e[m * 16 + j] : -9.0e15f;
        lv[j] = v;
        mx = fmaxf(mx, v);
    }
    float s = 0.0f;
#pragma unroll
    for (int j = 0; j < 16; ++j) s += expf(lv[j] - mx);
    const float dg = expf(lv[m] - mx) / s;

    float acc = 0.0f;
#pragma unroll
    for (int n = 0; n < 10; ++n) {
        float t2 = 0.0f;
#pragma unroll
        for (int m2 = 0; m2 < 10; ++m2)
            t2 += We[(o * 10 + n) * 320 + f * 10 + m2] * basis[n2 * 16 + m2];
        acc += basis[m * 16 + n] * t2;
    }
#pragma unroll
    for (int n = 0; n < 3; ++n) {
        float t2 = 0.0f;
#pragma unroll
        for (int m2 = 0; m2 < 3; ++m2)
            t2 += W2[(o * 3 + n) * 96 + f * 3 + m2] * basis[n2 * 16 + 10 + m2];
        acc += basis[m * 16 + 10 + n] * t2;
    }
#pragma unroll
    for (int n = 0; n < 3; ++n) {
        float t2 = 0.0f;
#pragma unroll
        for (int m2 = 0; m2 < 3; ++m2)
            t2 += W3[(o * 3 + n) * 96 + f * 3 + m2] * basis[n2 * 16 + 13 + m2];
        acc += basis[m * 16 + 13 + n] * t2;
    }

    const float Mv = dg * acc;

    const int ks = k >> 5;
    const int g  = (k >> 3) & 3;
    const int j  = k & 7;
    const int idx = ((ks * 32 + (c >> 4)) * 64 + ((c & 15) + 16 * g)) * 8 + j;
    Mfrag[idx] = (unsigned short)f2bfs(Mv);
}

// ---------------------------------------------------------------------------
// Kernel 2: Y[131072 x 512] = X[131072 x 512] @ M^T + bias
// Block: 512 threads (8 waves), BM=32 rows, grid 4096.
// Occupancy-first design: full-K A-tile staged ONCE as bf16 MFMA fragments
// (32 KB, lane-linear = 0 bank conflicts, cvt once per element), single
// __syncthreads, then a 16-step K-loop with NO barriers: per ks just
// 4 B dwordx4 (L2-resident Mfrag), 2 A ds_read_b128, 8 MFMA. LDS 34 KB +
// LB(512,8) (VGPR<=64) -> 4 blocks/CU = 32 waves/CU: cross-block TLP hides
// L2/HBM latency; block staging overlaps other blocks' compute.
// Epilogue: per-wave private LDS transpose (stride 68), NT dwordx4 stores.
// ---------------------------------------------------------------------------
__global__ __launch_bounds__(512, 8)
void gemm_kernel(const float* __restrict__ X,
                 const unsigned short* __restrict__ Mfrag,
                 const float* __restrict__ bias,
                 float* __restrict__ Y) {
    __shared__ float lds_f32[8704];                // 34816 B
    unsigned short* Afrag = reinterpret_cast<unsigned short*>(lds_f32);

    const int tid  = threadIdx.x;
    const int lane = tid & 63;
    const int wave = tid >> 6;        // 0..7
    const int l15  = lane & 15;
    const int g    = lane >> 4;       // 0..3
    const size_t rowbase = (size_t)blockIdx.x * 32;

    // ---- Stage full-K A-tile as bf16 fragments (cvt once) ----
    // frag f = ks*2+mi (0..31); entry (f,lane): row = (f&1)*16+(lane&15),
    // k = (f>>1)*32 + (lane>>4)*8; dst ushort = (f*64+lane)*8. Thread
    // (wave,lane) handles f = wave*4+i, i=0..3 -> lane-linear ds_write_b128.
    {
        const float* xb = X + rowbase * 512;
#pragma unroll
        for (int i = 0; i < 4; ++i) {
            const int f   = wave * 4 + i;
            const int row = (f & 1) * 16 + l15;
            const int k0  = (f >> 1) * 32 + g * 8;
            const float* src = xb + (size_t)row * 512 + k0;
            f32x4_t v0 = *reinterpret_cast<const f32x4_t*>(src);
            f32x4_t v1 = *reinterpret_cast<const f32x4_t*>(src + 4);
            bf16x8_t bv;
#pragma unroll
            for (int j = 0; j < 4; ++j) {
                bv[j]     = f2bfs(v0[j]);
                bv[j + 4] = f2bfs(v1[j]);
            }
            *reinterpret_cast<bf16x8_t*>(&Afrag[((f * 64) + lane) * 8]) = bv;
        }
    }
    __syncthreads();

    // ---- K-loop: no barriers, B-loads free to hoist ----
    const int colbase = wave * 64;
    const unsigned short* bp = Mfrag + ((size_t)((colbase >> 4) * 64) + lane) * 8;

    f32x4_t acc[2][4];
#pragma unroll
    for (int a = 0; a < 2; ++a)
#pragma unroll
        for (int b = 0; b < 4; ++b)
            acc[a][b] = (f32x4_t){0.f, 0.f, 0.f, 0.f};

#pragma unroll
    for (int ks = 0; ks < 16; ++ks) {
        bf16x8_t bfr[4];
#pragma unroll
        for (int ni = 0; ni < 4; ++ni)
            bfr[ni] = *reinterpret_cast<const bf16x8_t*>(bp + (size_t)ks * 16384 + ni * 512);
        bf16x8_t a[2];
#pragma unroll
        for (int mi = 0; mi < 2; ++mi)
            a[mi] = *reinterpret_cast<const bf16x8_t*>(&Afrag[((ks * 2 + mi) * 64 + lane) * 8]);
#pragma unroll
        for (int mi = 0; mi < 2; ++mi)
#pragma unroll
            for (int ni = 0; ni < 4; ++ni)
                acc[mi][ni] = __builtin_amdgcn_mfma_f32_16x16x32_bf16(
                    a[mi], bfr[ni], acc[mi][ni], 0, 0, 0);
    }

    __syncthreads();   // all Afrag reads done; reuse LDS as epilogue scratch

    // ---- Epilogue: per-wave private transpose (stride 68), NT stores ----
    constexpr int SW = 68;
    float* scr = lds_f32 + wave * (16 * SW);       // 1088 f32/wave, 8*1088=8704 ✓
    const float b_lo = bias[l15];
    const float b_hi = bias[16 + l15];

#pragma unroll
    for (int mi = 0; mi < 2; ++mi) {
#pragma unroll
        for (int ni = 0; ni < 4; ++ni) {
            const float bb = (ni & 1) ? b_hi : b_lo;
#pragma unroll
            for (int r = 0; r < 4; ++r)
                scr[(g * 4 + r) * SW + ni * 16 + l15] = acc[mi][ni][r] + bb;
        }
#pragma unroll
        for (int it = 0; it < 4; ++it) {
            const int flat = it * 64 + lane;   // 0..255
            const int row  = flat >> 4;        // 0..15
            const int c4   = flat & 15;
            f32x4_t v = *reinterpret_cast<const f32x4_t*>(&scr[row * SW + c4 * 4]);
            float* yp = Y + (rowbase + mi * 16 + row) * 512 + colbase + c4 * 4;
            __builtin_nontemporal_store(v, reinterpret_cast<f32x4_t*>(yp));
        }
    }
}

extern "C" void kernel_launch(void* const* d_in, const int* in_sizes, int n_in,
                              void* d_out, int out_size, void* d_ws, size_t ws_size,
                              hipStream_t stream) {
    const float* x     = (const float*)d_in[0];
    const float* basis = (const float*)d_in[1];
    const float* adj   = (const float*)d_in[2];
    const float* e     = (const float*)d_in[3];
    const float* We    = (const float*)d_in[4];
    const float* W2    = (const float*)d_in[5];
    const float* W3    = (const float*)d_in[6];
    const float* bias  = (const float*)d_in[7];

    unsigned short* Mfrag = (unsigned short*)d_ws;  // 512 KB needed
    if (ws_size < 512u * 512u * 2u) return;

    const int Bsz = in_sizes[0] / 512;              // 131072
    build_M_kernel<<<512, 512, 0, stream>>>(basis, adj, e, We, W2, W3, Mfrag);
    gemm_kernel<<<Bsz / 32, 512, 0, stream>>>(x, Mfrag, bias, (float*)d_out);
}

// Round 8
// 146.654 us; speedup vs baseline: 1.4685x; 1.4685x over previous
//
#include <hip/hip_runtime.h>
#include <hip/hip_bf16.h>

typedef __attribute__((ext_vector_type(4))) float f32x4_t;
typedef __attribute__((ext_vector_type(8))) short bf16x8_t;

__device__ __forceinline__ short f2bfs(float x) {
    union { __hip_bfloat16 h; short s; } u;
    u.h = __float2bfloat16(x);   // RNE
    return u.s;
}

// ---------------------------------------------------------------------------
// Kernel 1: build fused 512x512 operator M in fragment-major bf16 layout.
//   c = m*32+o (output col of GEMM), k = n2*32+f (contraction index)
//   M[c][k] = diag[m] * sum_{n,m2} basis[m,n] * Wbig[o,n,f,m2] * basis[n2,m2]
// B-fragment layout for mfma_f32_16x16x32_bf16:
//   flat ushort idx = ((ks*32 + c16)*64 + lane)*8 + j
//   value = M[c16*16 + (lane&15)][ks*32 + (lane>>4)*8 + j]
// ---------------------------------------------------------------------------
__global__ void build_M_kernel(const float* __restrict__ basis,
                               const float* __restrict__ adj,
                               const float* __restrict__ e,
                               const float* __restrict__ We,
                               const float* __restrict__ W2,
                               const float* __restrict__ W3,
                               unsigned short* __restrict__ Mfrag) {
    const int t = blockIdx.x * blockDim.x + threadIdx.x;  // 0..262143
    const int c = t >> 9;           // 0..511
    const int k = t & 511;
    const int m  = c >> 5, o = c & 31;
    const int n2 = k >> 5, f = k & 31;

    float lv[16];
    float mx = -3.4e38f;
#pragma unroll
    for (int j = 0; j < 16; ++j) {
        float a = adj[m * 16 + j];
        float v = (a > 0.0f) ? e[m * 16 + j] : -9.0e15f;
        lv[j] = v;
        mx = fmaxf(mx, v);
    }
    float s = 0.0f;
#pragma unroll
    for (int j = 0; j < 16; ++j) s += expf(lv[j] - mx);
    const float dg = expf(lv[m] - mx) / s;

    float acc = 0.0f;
#pragma unroll
    for (int n = 0; n < 10; ++n) {
        float t2 = 0.0f;
#pragma unroll
        for (int m2 = 0; m2 < 10; ++m2)
            t2 += We[(o * 10 + n) * 320 + f * 10 + m2] * basis[n2 * 16 + m2];
        acc += basis[m * 16 + n] * t2;
    }
#pragma unroll
    for (int n = 0; n < 3; ++n) {
        float t2 = 0.0f;
#pragma unroll
        for (int m2 = 0; m2 < 3; ++m2)
            t2 += W2[(o * 3 + n) * 96 + f * 3 + m2] * basis[n2 * 16 + 10 + m2];
        acc += basis[m * 16 + 10 + n] * t2;
    }
#pragma unroll
    for (int n = 0; n < 3; ++n) {
        float t2 = 0.0f;
#pragma unroll
        for (int m2 = 0; m2 < 3; ++m2)
            t2 += W3[(o * 3 + n) * 96 + f * 3 + m2] * basis[n2 * 16 + 13 + m2];
        acc += basis[m * 16 + 13 + n] * t2;
    }

    const float Mv = dg * acc;

    const int ks = k >> 5;
    const int g  = (k >> 3) & 3;
    const int j  = k & 7;
    const int idx = ((ks * 32 + (c >> 4)) * 64 + ((c & 15) + 16 * g)) * 8 + j;
    Mfrag[idx] = (unsigned short)f2bfs(Mv);
}

// ---------------------------------------------------------------------------
// Kernel 2: Y[131072 x 512] = X[131072 x 512] @ M^T + bias
// Block: 512 threads (8 waves), BM=32 rows, grid 4096.
// Same structure as R7's kernel G (full-K bf16-fragment staging, single
// barrier, barrier-free 16-step K-loop) but __launch_bounds__(512,4):
// G's (512,8) capped VGPR at 32 -> acc alone spilled to scratch (WRITE
// 360 MB, MfmaUtil 11.5%). With cap ~128 the loop fits in ~64 VGPR, no
// spills; LDS 34.8 KB still admits 4 blocks/CU = 32 waves/CU if VGPR<=64.
// K-loop per ks: 4 B dwordx4 (L2-resident Mfrag), 2 A ds_read_b128
// (lane-linear, 0 conflicts), 8 MFMA. No barriers -> B-loads hoistable,
// cross-block TLP hides L2 latency.
// Epilogue: per-wave private LDS transpose (stride 68), NT dwordx4 stores.
// ---------------------------------------------------------------------------
__global__ __launch_bounds__(512, 4)
void gemm_kernel(const float* __restrict__ X,
                 const unsigned short* __restrict__ Mfrag,
                 const float* __restrict__ bias,
                 float* __restrict__ Y) {
    __shared__ float lds_f32[8704];                // 34816 B
    unsigned short* Afrag = reinterpret_cast<unsigned short*>(lds_f32);

    const int tid  = threadIdx.x;
    const int lane = tid & 63;
    const int wave = tid >> 6;        // 0..7
    const int l15  = lane & 15;
    const int g    = lane >> 4;       // 0..3
    const size_t rowbase = (size_t)blockIdx.x * 32;

    // ---- Stage full-K A-tile as bf16 fragments (cvt once) ----
    // frag f = ks*2+mi (0..31); entry (f,lane): row = (f&1)*16+(lane&15),
    // k = (f>>1)*32 + (lane>>4)*8; dst ushort = (f*64+lane)*8. Thread
    // (wave,lane) handles f = wave*4+i, i=0..3 -> lane-linear ds_write_b128.
    {
        const float* xb = X + rowbase * 512;
#pragma unroll
        for (int i = 0; i < 4; ++i) {
            const int f   = wave * 4 + i;
            const int row = (f & 1) * 16 + l15;
            const int k0  = (f >> 1) * 32 + g * 8;
            const float* src = xb + (size_t)row * 512 + k0;
            f32x4_t v0 = *reinterpret_cast<const f32x4_t*>(src);
            f32x4_t v1 = *reinterpret_cast<const f32x4_t*>(src + 4);
            bf16x8_t bv;
#pragma unroll
            for (int j = 0; j < 4; ++j) {
                bv[j]     = f2bfs(v0[j]);
                bv[j + 4] = f2bfs(v1[j]);
            }
            *reinterpret_cast<bf16x8_t*>(&Afrag[((f * 64) + lane) * 8]) = bv;
        }
    }
    __syncthreads();

    // ---- K-loop: no barriers, B-loads free to hoist ----
    const int colbase = wave * 64;
    const unsigned short* bp = Mfrag + ((size_t)((colbase >> 4) * 64) + lane) * 8;

    f32x4_t acc[2][4];
#pragma unroll
    for (int a = 0; a < 2; ++a)
#pragma unroll
        for (int b = 0; b < 4; ++b)
            acc[a][b] = (f32x4_t){0.f, 0.f, 0.f, 0.f};

#pragma unroll
    for (int ks = 0; ks < 16; ++ks) {
        bf16x8_t bfr[4];
#pragma unroll
        for (int ni = 0; ni < 4; ++ni)
            bfr[ni] = *reinterpret_cast<const bf16x8_t*>(bp + (size_t)ks * 16384 + ni * 512);
        bf16x8_t a[2];
#pragma unroll
        for (int mi = 0; mi < 2; ++mi)
            a[mi] = *reinterpret_cast<const bf16x8_t*>(&Afrag[((ks * 2 + mi) * 64 + lane) * 8]);
#pragma unroll
        for (int mi = 0; mi < 2; ++mi)
#pragma unroll
            for (int ni = 0; ni < 4; ++ni)
                acc[mi][ni] = __builtin_amdgcn_mfma_f32_16x16x32_bf16(
                    a[mi], bfr[ni], acc[mi][ni], 0, 0, 0);
    }

    __syncthreads();   // all Afrag reads done; reuse LDS as epilogue scratch

    // ---- Epilogue: per-wave private transpose (stride 68), NT stores ----
    constexpr int SW = 68;
    float* scr = lds_f32 + wave * (16 * SW);       // 1088 f32/wave, 8*1088=8704 ✓
    const float b_lo = bias[l15];
    const float b_hi = bias[16 + l15];

#pragma unroll
    for (int mi = 0; mi < 2; ++mi) {
#pragma unroll
        for (int ni = 0; ni < 4; ++ni) {
            const float bb = (ni & 1) ? b_hi : b_lo;
#pragma unroll
            for (int r = 0; r < 4; ++r)
                scr[(g * 4 + r) * SW + ni * 16 + l15] = acc[mi][ni][r] + bb;
        }
#pragma unroll
        for (int it = 0; it < 4; ++it) {
            const int flat = it * 64 + lane;   // 0..255
            const int row  = flat >> 4;        // 0..15
            const int c4   = flat & 15;
            f32x4_t v = *reinterpret_cast<const f32x4_t*>(&scr[row * SW + c4 * 4]);
            float* yp = Y + (rowbase + mi * 16 + row) * 512 + colbase + c4 * 4;
            __builtin_nontemporal_store(v, reinterpret_cast<f32x4_t*>(yp));
        }
    }
}

extern "C" void kernel_launch(void* const* d_in, const int* in_sizes, int n_in,
                              void* d_out, int out_size, void* d_ws, size_t ws_size,
                              hipStream_t stream) {
    const float* x     = (const float*)d_in[0];
    const float* basis = (const float*)d_in[1];
    const float* adj   = (const float*)d_in[2];
    const float* e     = (const float*)d_in[3];
    const float* We    = (const float*)d_in[4];
    const float* W2    = (const float*)d_in[5];
    const float* W3    = (const float*)d_in[6];
    const float* bias  = (const float*)d_in[7];

    unsigned short* Mfrag = (unsigned short*)d_ws;  // 512 KB needed
    if (ws_size < 512u * 512u * 2u) return;

    const int Bsz = in_sizes[0] / 512;              // 131072
    build_M_kernel<<<512, 512, 0, stream>>>(basis, adj, e, We, W2, W3, Mfrag);
    gemm_kernel<<<Bsz / 32, 512, 0, stream>>>(x, Mfrag, bias, (float*)d_out);
}